// Round 2
// baseline (5041.057 us; speedup 1.0000x reference)
//
#include <hip/hip_runtime.h>
#include <hip/hip_bf16.h>
#include <math.h>

// NEZHA-style 4-layer encoder, B=16 S=512 D=768 H=12 DH=64 FF=3072.
// Reference dtypes: float32 in / float32 out. Internal compute: bf16 MFMA.

typedef __bf16 bf16x8 __attribute__((ext_vector_type(8)));
typedef __bf16 bf16x4 __attribute__((ext_vector_type(4)));
typedef float  floatx4 __attribute__((ext_vector_type(4)));

constexpr int Bb = 16, Ss = 512, Dd = 768, Hh = 12, DH = 64, FF = 3072, Ll = 4;
constexpr int BH  = Bb * Hh;       // 192 (batch*heads)
constexpr int RLD = 160;           // padded rel-bucket dim (129 -> 160, mult of 32)
constexpr int PLD = Ss + RLD;      // 672: probs row = [probs(512) | Prow(160)]
constexpr float LN_EPS = 1e-12f;

__device__ inline float wredsum(float v) {
#pragma unroll
  for (int o = 32; o > 0; o >>= 1) v += __shfl_xor(v, o, 64);
  return v;
}
__device__ inline float wredmax(float v) {
#pragma unroll
  for (int o = 32; o > 0; o >>= 1) v = fmaxf(v, __shfl_xor(v, o, 64));
  return v;
}

enum { E_QK, E_VT, E_R, E_SC, E_CTX, E_RES, E_GELU };

// C = A(M,K) @ B(N,K)^T, NT form. Per-wave 16x64 tile, MFMA 16x16x32 bf16,
// operands loaded straight from global (16B/lane). Verified lane mappings:
//   A/B frag: row = lane&15, k = (lane>>4)*8 + j   (j=0..7)
//   C/D:      col = lane&15, row = (lane>>4)*4 + r (r=0..3)
template <int EPI, int M, int N, int K, int LDA, int LDB>
__global__ __launch_bounds__(256) void gemm_nt(
    const __bf16* __restrict__ A, const __bf16* __restrict__ B,
    const float* __restrict__ bias, const __bf16* __restrict__ aux,
    const int* __restrict__ mask, __bf16* __restrict__ out)
{
  constexpr int MT  = M / 16;
  constexpr int NT4 = (N + 63) / 64;
  const int lane = threadIdx.x & 63;
  const int wid  = threadIdx.x >> 6;
  const int tile = blockIdx.x * 4 + wid;
  if (tile >= MT * NT4) return;
  const int im = tile / NT4, in = tile % NT4;
  const int z = blockIdx.y;
  int b = 0, h = 0;
  size_t aoff = 0, boff = 0;
  if constexpr (EPI == E_R) {
    b = z / Hh; h = z % Hh;
    aoff = (size_t)b * Ss * Dd + h * DH;           // Q rows for (b,h), lda=768
  } else if constexpr (EPI == E_SC) {
    b = z / Hh; h = z % Hh;
    aoff = (size_t)b * Ss * Dd + h * DH;
    boff = aoff;                                    // K rows for (b,h)
  } else if constexpr (EPI == E_CTX) {
    b = z / Hh; h = z % Hh;
    aoff = (size_t)z * Ss * PLD;                    // probs_ext rows
    boff = (size_t)z * DH * PLD;                    // [V^T | T^T] rows
  }

  const __bf16* Ap = A + aoff + (size_t)(im * 16 + (lane & 15)) * LDA + ((lane >> 4) * 8);
  const __bf16* Bp = B + boff + (size_t)(lane & 15) * LDB + ((lane >> 4) * 8);

  floatx4 acc[4] = {};
  for (int k = 0; k < K; k += 32) {
    bf16x8 av = *(const bf16x8*)(Ap + k);
#pragma unroll
    for (int t = 0; t < 4; ++t) {
      bf16x8 bv = *(const bf16x8*)(Bp + (size_t)(in * 64 + t * 16) * LDB + k);
      acc[t] = __builtin_amdgcn_mfma_f32_16x16x32_bf16(av, bv, acc[t], 0, 0, 0);
    }
  }

  const int mb = im * 16 + ((lane >> 4) << 2);
#pragma unroll
  for (int t = 0; t < 4; ++t) {
    const int n = in * 64 + t * 16 + (lane & 15);
    if constexpr (N % 64 != 0) { if (n >= N) continue; }
    if constexpr (EPI == E_QK) {
      const float bv2 = bias[n];
#pragma unroll
      for (int r = 0; r < 4; ++r)
        out[(size_t)(mb + r) * Dd + n] = (__bf16)(acc[t][r] + bv2);
    } else if constexpr (EPI == E_VT) {
      const float bv2 = bias[n];
      const int hh2 = n >> 6, d = n & 63;
#pragma unroll
      for (int r = 0; r < 4; ++r) {
        const int m = mb + r, bb = m >> 9, s = m & 511;
        out[((size_t)(bb * Hh + hh2) * DH + d) * PLD + s] = (__bf16)(acc[t][r] + bv2);
      }
    } else if constexpr (EPI == E_R) {
#pragma unroll
      for (int r = 0; r < 4; ++r)
        out[((size_t)z * Ss + mb + r) * RLD + n] = (__bf16)(acc[t][r]);
    } else if constexpr (EPI == E_SC) {
      const float mbias = (1.0f - (float)mask[b * Ss + n]) * -10000.0f;
#pragma unroll
      for (int r = 0; r < 4; ++r) {
        const int q = mb + r;
        int rr = n - q; rr = rr < -64 ? -64 : (rr > 64 ? 64 : rr); rr += 64;
        const float rv = (float)aux[((size_t)z * Ss + q) * RLD + rr];
        out[((size_t)z * Ss + q) * PLD + n] = (__bf16)((acc[t][r] + rv) * 0.125f + mbias);
      }
    } else if constexpr (EPI == E_CTX) {
#pragma unroll
      for (int r = 0; r < 4; ++r) {
        const int q = mb + r;
        out[(size_t)(b * Ss + q) * Dd + h * DH + n] = (__bf16)(acc[t][r]);
      }
    } else if constexpr (EPI == E_RES) {
      const float bv2 = bias[n];
#pragma unroll
      for (int r = 0; r < 4; ++r) {
        const int m = mb + r;
        out[(size_t)m * Dd + n] = (__bf16)(acc[t][r] + bv2 + (float)aux[(size_t)m * Dd + n]);
      }
    } else if constexpr (EPI == E_GELU) {
      const float bv2 = bias[n];
#pragma unroll
      for (int r = 0; r < 4; ++r) {
        const float x = acc[t][r] + bv2;
        out[(size_t)(mb + r) * FF + n] =
            (__bf16)(0.5f * x * (1.0f + erff(x * 0.7071067811865475f)));
      }
    }
  }
}

// softmax over scores row (512, bf16 in-place -> probs) + Prow bucket sums
// into [512:672]: r=0 tail (k<=q-64), r=128 tail (k>=q+64), r=1..127 gather.
__global__ __launch_bounds__(256) void softmax_rel(__bf16* __restrict__ pbuf)
{
  __shared__ float sm[4][512];
  const int lane = threadIdx.x & 63, wid = threadIdx.x >> 6;
  const size_t row = (size_t)blockIdx.x * 4 + wid;  // < 192*512
  const int q = (int)(row & (Ss - 1));
  __bf16* p = pbuf + row * PLD;
  bf16x8 sv = *(const bf16x8*)(p + lane * 8);
  float x[8], mx = -3.0e38f;
#pragma unroll
  for (int j = 0; j < 8; ++j) { x[j] = (float)sv[j]; mx = fmaxf(mx, x[j]); }
  mx = wredmax(mx);
  float s = 0.f;
#pragma unroll
  for (int j = 0; j < 8; ++j) { x[j] = __expf(x[j] - mx); s += x[j]; }
  s = wredsum(s);
  const float inv = 1.0f / s;
  float t0 = 0.f, t1 = 0.f;
  const int base = lane * 8;
  bf16x8 ov;
#pragma unroll
  for (int j = 0; j < 8; ++j) {
    const float pv = x[j] * inv;
    ov[j] = (__bf16)pv;
    sm[wid][base + j] = pv;
    const int kk = base + j;
    if (kk <= q - 64) t0 += pv;
    if (kk >= q + 64) t1 += pv;
  }
  *(bf16x8*)(p + lane * 8) = ov;
  t0 = wredsum(t0);
  t1 = wredsum(t1);
  __syncthreads();
  for (int r = lane; r < RLD; r += 64) {
    float v;
    if (r == 0) v = t0;
    else if (r == 128) v = t1;
    else if (r < 128) { const int kk = q + r - 64; v = (kk >= 0 && kk < Ss) ? sm[wid][kk] : 0.f; }
    else v = 0.f;
    p[Ss + r] = (__bf16)v;
  }
}

template <typename OutT>
__global__ __launch_bounds__(256) void ln_rows(
    const __bf16* __restrict__ x, const float* __restrict__ wv,
    const float* __restrict__ bv, OutT* __restrict__ out)
{
  __shared__ float red[4];
  const int row = blockIdx.x, t = threadIdx.x;
  const __bf16* xr = x + (size_t)row * Dd;
  float xv[3], s = 0.f;
#pragma unroll
  for (int j = 0; j < 3; ++j) { xv[j] = (float)xr[t + 256 * j]; s += xv[j]; }
  s = wredsum(s);
  if ((t & 63) == 0) red[t >> 6] = s;
  __syncthreads();
  const float mean = (red[0] + red[1] + red[2] + red[3]) * (1.0f / Dd);
  __syncthreads();
  float qq = 0.f;
#pragma unroll
  for (int j = 0; j < 3; ++j) { const float d = xv[j] - mean; qq += d * d; }
  qq = wredsum(qq);
  if ((t & 63) == 0) red[t >> 6] = qq;
  __syncthreads();
  const float var = (red[0] + red[1] + red[2] + red[3]) * (1.0f / Dd);
  const float rs = rsqrtf(var + LN_EPS);
#pragma unroll
  for (int j = 0; j < 3; ++j) {
    const int i = t + 256 * j;
    out[(size_t)row * Dd + i] = (OutT)((xv[j] - mean) * rs * wv[i] + bv[i]);
  }
}

__global__ __launch_bounds__(256) void embed_ln(
    const int* __restrict__ ids, const int* __restrict__ tts,
    const float* __restrict__ we, const float* __restrict__ te,
    const float* __restrict__ wv, const float* __restrict__ bv,
    __bf16* __restrict__ out)
{
  __shared__ float red[4];
  const int row = blockIdx.x, t = threadIdx.x;
  const int id = ids[row], tt = tts[row];
  const float* wr = we + (size_t)id * Dd;
  const float* tr = te + (size_t)tt * Dd;
  float xv[3], s = 0.f;
#pragma unroll
  for (int j = 0; j < 3; ++j) {
    const int i = t + 256 * j;
    xv[j] = wr[i] + tr[i];
    s += xv[j];
  }
  s = wredsum(s);
  if ((t & 63) == 0) red[t >> 6] = s;
  __syncthreads();
  const float mean = (red[0] + red[1] + red[2] + red[3]) * (1.0f / Dd);
  __syncthreads();
  float qq = 0.f;
#pragma unroll
  for (int j = 0; j < 3; ++j) { const float d = xv[j] - mean; qq += d * d; }
  qq = wredsum(qq);
  if ((t & 63) == 0) red[t >> 6] = qq;
  __syncthreads();
  const float var = (red[0] + red[1] + red[2] + red[3]) * (1.0f / Dd);
  const float rs = rsqrtf(var + LN_EPS);
#pragma unroll
  for (int j = 0; j < 3; ++j) {
    const int i = t + 256 * j;
    out[(size_t)row * Dd + i] = (__bf16)((xv[j] - mean) * rs * wv[i] + bv[i]);
  }
}

// fp32 -> bf16 bulk convert (n % 4 == 0)
__global__ __launch_bounds__(256) void f2b(
    const float* __restrict__ in, __bf16* __restrict__ out, int n4)
{
  const int i = blockIdx.x * 256 + threadIdx.x;
  if (i >= n4) return;
  const float4 v = ((const float4*)in)[i];
  bf16x4 o;
  o[0] = (__bf16)v.x; o[1] = (__bf16)v.y; o[2] = (__bf16)v.z; o[3] = (__bf16)v.w;
  *(bf16x4*)(out + (size_t)i * 4) = o;
}

// Fill the T^T block of vte: vte[bh][d][512+r] = rel[64][r][d] (r<129), else 0.
__global__ __launch_bounds__(256) void prep_rel(
    const float* __restrict__ rel, __bf16* __restrict__ vte)
{
  const int idx = blockIdx.x * 256 + threadIdx.x;
  constexpr int TOT = BH * DH * RLD;
  if (idx >= TOT) return;
  const int r = idx % RLD, t2 = idx / RLD;
  const int d = t2 % DH, bh = t2 / DH;
  __bf16 v = (__bf16)0.f;
  if (r < 129) v = (__bf16)rel[((size_t)(64 * Ss + r)) * DH + d];
  vte[((size_t)bh * DH + d) * PLD + Ss + r] = v;
}

// Tb[r][d] = rel[64][r][d] for r<129 else 0; 192 rows (E_R reads up to 191).
__global__ __launch_bounds__(256) void rel2b(
    const float* __restrict__ rel, __bf16* __restrict__ Tb)
{
  const int idx = blockIdx.x * 256 + threadIdx.x;  // < 192*64
  const int d = idx & 63, r = idx >> 6;
  float v = (r < 129) ? rel[((size_t)(64 * Ss + r)) * DH + d] : 0.f;
  Tb[idx] = (__bf16)v;
}

extern "C" void kernel_launch(void* const* d_in, const int* in_sizes, int n_in,
                              void* d_out, int out_size, void* d_ws, size_t ws_size,
                              hipStream_t stream)
{
  (void)in_sizes; (void)n_in; (void)out_size; (void)ws_size;
  const int*   ids  = (const int*)d_in[0];
  const int*   mask = (const int*)d_in[1];
  const int*   tts  = (const int*)d_in[2];
  const float* wemb = (const float*)d_in[3];
  const float* temb = (const float*)d_in[4];
  const float* elw  = (const float*)d_in[5];
  const float* elb  = (const float*)d_in[6];
  const float* qw   = (const float*)d_in[7];
  const float* qb   = (const float*)d_in[8];
  const float* kw   = (const float*)d_in[9];
  const float* kb   = (const float*)d_in[10];
  const float* vw   = (const float*)d_in[11];
  const float* vb   = (const float*)d_in[12];
  const float* rel  = (const float*)d_in[13];
  const float* aow  = (const float*)d_in[14];
  const float* aob  = (const float*)d_in[15];
  const float* alw  = (const float*)d_in[16];
  const float* alb  = (const float*)d_in[17];
  const float* iw   = (const float*)d_in[18];
  const float* ib   = (const float*)d_in[19];
  const float* ow   = (const float*)d_in[20];
  const float* ob   = (const float*)d_in[21];
  const float* olw  = (const float*)d_in[22];
  const float* olb  = (const float*)d_in[23];

  char* wsb = (char*)d_ws;
  size_t off = 0;
  auto alloc = [&](size_t elems) {
    __bf16* p = (__bf16*)(wsb + off);
    off += elems * sizeof(__bf16);
    return p;
  };
  constexpr size_t HB  = (size_t)Bb * Ss * Dd;         // 6.29M elems
  constexpr size_t WQ  = (size_t)Ll * Dd * Dd;         // 2.36M
  constexpr size_t WI  = (size_t)Ll * FF * Dd;         // 9.44M
  __bf16* qw_b = alloc(WQ);
  __bf16* kw_b = alloc(WQ);
  __bf16* vw_b = alloc(WQ);
  __bf16* aw_b = alloc(WQ);
  __bf16* iw_b = alloc(WI);
  __bf16* ow_b = alloc(WI);
  __bf16* hbuf = alloc(HB);                            // hidden state
  __bf16* abuf = alloc(HB);                            // attn-LN output
  __bf16* qbuf = alloc(HB);                            // also aliased as s1
  __bf16* kbuf = alloc(HB);
  __bf16* ctx  = alloc(HB);
  __bf16* vte  = alloc((size_t)BH * DH * PLD);         // [V^T | T^T] per (b,h)
  __bf16* pb   = alloc((size_t)BH * Ss * PLD);         // [scores/probs | Prow]
  __bf16* fbuf = alloc((size_t)Bb * Ss * FF);          // GELU out; Rb aliases
  __bf16* Tb   = alloc((size_t)192 * DH);              // bf16 rel table (192 rows)
  __bf16* s1   = qbuf;                                 // alias: qbuf free after E_SC
  __bf16* Rb   = fbuf;                                 // alias: fbuf free until E_GELU
  // total ~300 MiB

  f2b<<<(int)((WQ / 4 + 255) / 256), 256, 0, stream>>>(qw, qw_b, (int)(WQ / 4));
  f2b<<<(int)((WQ / 4 + 255) / 256), 256, 0, stream>>>(kw, kw_b, (int)(WQ / 4));
  f2b<<<(int)((WQ / 4 + 255) / 256), 256, 0, stream>>>(vw, vw_b, (int)(WQ / 4));
  f2b<<<(int)((WQ / 4 + 255) / 256), 256, 0, stream>>>(aow, aw_b, (int)(WQ / 4));
  f2b<<<(int)((WI / 4 + 255) / 256), 256, 0, stream>>>(iw, iw_b, (int)(WI / 4));
  f2b<<<(int)((WI / 4 + 255) / 256), 256, 0, stream>>>(ow, ow_b, (int)(WI / 4));
  rel2b<<<(192 * DH) / 256, 256, 0, stream>>>(rel, Tb);
  prep_rel<<<(BH * DH * RLD + 255) / 256, 256, 0, stream>>>(rel, vte);
  embed_ln<<<Bb * Ss, 256, 0, stream>>>(ids, tts, wemb, temb, elw, elb, hbuf);

  for (int l = 0; l < Ll; ++l) {
    const __bf16* qwl = qw_b + (size_t)l * Dd * Dd;  const float* qbl = qb + (size_t)l * Dd;
    const __bf16* kwl = kw_b + (size_t)l * Dd * Dd;  const float* kbl = kb + (size_t)l * Dd;
    const __bf16* vwl = vw_b + (size_t)l * Dd * Dd;  const float* vbl = vb + (size_t)l * Dd;
    const __bf16* awl = aw_b + (size_t)l * Dd * Dd;  const float* abl = aob + (size_t)l * Dd;
    const float*  lw1 = alw + (size_t)l * Dd;        const float* lb1 = alb + (size_t)l * Dd;
    const __bf16* iwl = iw_b + (size_t)l * FF * Dd;  const float* ibl = ib + (size_t)l * FF;
    const __bf16* owl = ow_b + (size_t)l * Dd * FF;  const float* obl = ob + (size_t)l * Dd;
    const float*  lw2 = olw + (size_t)l * Dd;        const float* lb2 = olb + (size_t)l * Dd;

    gemm_nt<E_QK, 8192, 768, 768, 768, 768><<<dim3(1536, 1), 256, 0, stream>>>(
        hbuf, qwl, qbl, nullptr, nullptr, qbuf);
    gemm_nt<E_QK, 8192, 768, 768, 768, 768><<<dim3(1536, 1), 256, 0, stream>>>(
        hbuf, kwl, kbl, nullptr, nullptr, kbuf);
    gemm_nt<E_VT, 8192, 768, 768, 768, 768><<<dim3(1536, 1), 256, 0, stream>>>(
        hbuf, vwl, vbl, nullptr, nullptr, vte);
    gemm_nt<E_R, 512, 129, 64, 768, 64><<<dim3(24, BH), 256, 0, stream>>>(
        qbuf, Tb, nullptr, nullptr, nullptr, Rb);
    gemm_nt<E_SC, 512, 512, 64, 768, 768><<<dim3(64, BH), 256, 0, stream>>>(
        qbuf, kbuf, nullptr, Rb, mask, pb);
    softmax_rel<<<BH * Ss / 4, 256, 0, stream>>>(pb);
    gemm_nt<E_CTX, 512, 64, 672, 672, 672><<<dim3(8, BH), 256, 0, stream>>>(
        pb, vte, nullptr, nullptr, nullptr, ctx);
    gemm_nt<E_RES, 8192, 768, 768, 768, 768><<<dim3(1536, 1), 256, 0, stream>>>(
        ctx, awl, abl, hbuf, nullptr, s1);
    ln_rows<__bf16><<<8192, 256, 0, stream>>>(s1, lw1, lb1, abuf);
    gemm_nt<E_GELU, 8192, 3072, 768, 768, 768><<<dim3(6144, 1), 256, 0, stream>>>(
        abuf, iwl, ibl, nullptr, nullptr, fbuf);
    gemm_nt<E_RES, 8192, 768, 3072, 3072, 3072><<<dim3(1536, 1), 256, 0, stream>>>(
        fbuf, owl, obl, abuf, nullptr, s1);
    if (l == Ll - 1)
      ln_rows<float><<<8192, 256, 0, stream>>>(s1, lw2, lb2, (float*)d_out);
    else
      ln_rows<__bf16><<<8192, 256, 0, stream>>>(s1, lw2, lb2, hbuf);
  }
}

// Round 3
// 2232.401 us; speedup vs baseline: 2.2581x; 2.2581x over previous
//
#include <hip/hip_runtime.h>
#include <hip/hip_bf16.h>
#include <math.h>

// NEZHA-style 4-layer encoder, B=16 S=512 D=768 H=12 DH=64 FF=3072.
// Reference dtypes: float32 in / float32 out. Internal compute: bf16 MFMA.
// R3: m97-style 128x128 LDS-staged GEMM (global_load_lds width=16) for the
// big GEMMs; QKV fused into one N=2304 launch.

typedef __bf16 bf16x8 __attribute__((ext_vector_type(8)));
typedef __bf16 bf16x4 __attribute__((ext_vector_type(4)));
typedef float  floatx4 __attribute__((ext_vector_type(4)));

constexpr int Bb = 16, Ss = 512, Dd = 768, Hh = 12, DH = 64, FF = 3072, Ll = 4;
constexpr int BH  = Bb * Hh;       // 192 (batch*heads)
constexpr int RLD = 160;           // padded rel-bucket dim (129 -> 160)
constexpr int PLD = Ss + RLD;      // 672: probs row = [probs(512) | Prow(160)]
constexpr float LN_EPS = 1e-12f;

__device__ inline float wredsum(float v) {
#pragma unroll
  for (int o = 32; o > 0; o >>= 1) v += __shfl_xor(v, o, 64);
  return v;
}
__device__ inline float wredmax(float v) {
#pragma unroll
  for (int o = 32; o > 0; o >>= 1) v = fmaxf(v, __shfl_xor(v, o, 64));
  return v;
}

__device__ inline void gload_lds16(const __bf16* gp, __bf16* lp) {
  __builtin_amdgcn_global_load_lds(
      (const __attribute__((address_space(1))) void*)gp,
      (__attribute__((address_space(3))) void*)lp, 16, 0, 0);
}

enum { E_QK, E_VT, E_R, E_SC, E_CTX, E_RES, E_GELU, E_QKV };

// ---------------------------------------------------------------------------
// m97-style LDS-staged GEMM: C(M,N) = A(M,K) @ B(N,K)^T.  Block = 256 thr =
// 4 waves; 128x128 C-tile; each wave 64x64 (4x4 MFMA 16x16x32 acc).  BK=64
// staged via global_load_lds dwordx4 (wave-uniform LDS base + lane*16).
// Fragment maps (HW-verified): A/B row = lane&15, k = (lane>>4)*8+j;
// C/D col = lane&15, row = (lane>>4)*4+r.
// ---------------------------------------------------------------------------
template <int EPI, int N, int K>
__global__ __launch_bounds__(256) void gemm128(
    const __bf16* __restrict__ A, const __bf16* __restrict__ B,
    const float* __restrict__ b0, const float* __restrict__ b1,
    const float* __restrict__ b2, const __bf16* __restrict__ aux,
    __bf16* __restrict__ o0, __bf16* __restrict__ o1, __bf16* __restrict__ o2)
{
  __shared__ __bf16 As[128 * 64];
  __shared__ __bf16 Bs[128 * 64];
  const int t = threadIdx.x;
  const int lane = t & 63, wid = t >> 6;
  constexpr int NT = N / 128;
  const int tm = blockIdx.x / NT, tn = blockIdx.x % NT;

  const __bf16* Ag = A + (size_t)(tm * 128) * K;
  const __bf16* Bg = B + (size_t)(tn * 128) * K;

  const int srow = t >> 3;          // 0..31: staged row within 32-row chunk
  const int scol = (t & 7) * 8;     // k-offset of this thread's 16B

  const int wm = (wid >> 1) * 64, wn = (wid & 1) * 64;
  const int fr = lane & 15, fk = (lane >> 4) * 8;

  floatx4 acc[4][4] = {};

  for (int k0 = 0; k0 < K; k0 += 64) {
    __syncthreads();
#pragma unroll
    for (int j = 0; j < 4; ++j) {
      const int row = j * 32 + srow;
      const int ldsrow = j * 32 + wid * 8;              // wave-uniform base row
      gload_lds16(Ag + (size_t)row * K + k0 + scol, As + ldsrow * 64);
      gload_lds16(Bg + (size_t)row * K + k0 + scol, Bs + ldsrow * 64);
    }
    __syncthreads();
#pragma unroll
    for (int kk = 0; kk < 64; kk += 32) {
      bf16x8 af[4], bfv[4];
#pragma unroll
      for (int i = 0; i < 4; ++i) {
        af[i]  = *(const bf16x8*)(As + (wm + i * 16 + fr) * 64 + kk + fk);
        bfv[i] = *(const bf16x8*)(Bs + (wn + i * 16 + fr) * 64 + kk + fk);
      }
#pragma unroll
      for (int i = 0; i < 4; ++i)
#pragma unroll
        for (int j = 0; j < 4; ++j)
          acc[i][j] = __builtin_amdgcn_mfma_f32_16x16x32_bf16(af[i], bfv[j],
                                                              acc[i][j], 0, 0, 0);
    }
  }

  const int rbase = (lane >> 4) << 2;
  const int cl = lane & 15;

  if constexpr (EPI == E_QKV) {
    // N = 2304 = [Q(768) | K(768) | V(768)]; 128-tiles never cross a 768 edge.
    const int which = (tn * 128) / Dd;
    const float* bias = which == 0 ? b0 : (which == 1 ? b1 : b2);
#pragma unroll
    for (int j = 0; j < 4; ++j) {
      const int col = tn * 128 + wn + j * 16 + cl - which * Dd;
      const float bv = bias[col];
#pragma unroll
      for (int i = 0; i < 4; ++i)
#pragma unroll
        for (int r = 0; r < 4; ++r) {
          const int m = tm * 128 + wm + i * 16 + rbase + r;
          const float v = acc[i][j][r] + bv;
          if (which == 2) {   // V -> transposed [V^T | T^T] layout
            const int hh = col >> 6, d = col & 63;
            const int bb = m >> 9, s = m & 511;
            o2[((size_t)(bb * Hh + hh) * DH + d) * PLD + s] = (__bf16)v;
          } else {
            (which == 0 ? o0 : o1)[(size_t)m * Dd + col] = (__bf16)v;
          }
        }
    }
  } else if constexpr (EPI == E_RES) {
#pragma unroll
    for (int j = 0; j < 4; ++j) {
      const int n = tn * 128 + wn + j * 16 + cl;
      const float bv = b0[n];
#pragma unroll
      for (int i = 0; i < 4; ++i)
#pragma unroll
        for (int r = 0; r < 4; ++r) {
          const int m = tm * 128 + wm + i * 16 + rbase + r;
          o0[(size_t)m * Dd + n] =
              (__bf16)(acc[i][j][r] + bv + (float)aux[(size_t)m * Dd + n]);
        }
    }
  } else if constexpr (EPI == E_GELU) {
#pragma unroll
    for (int j = 0; j < 4; ++j) {
      const int n = tn * 128 + wn + j * 16 + cl;
      const float bv = b0[n];
#pragma unroll
      for (int i = 0; i < 4; ++i)
#pragma unroll
        for (int r = 0; r < 4; ++r) {
          const int m = tm * 128 + wm + i * 16 + rbase + r;
          const float x = acc[i][j][r] + bv;
          o0[(size_t)m * FF + n] =
              (__bf16)(0.5f * x * (1.0f + erff(x * 0.7071067811865475f)));
        }
    }
  }
}

// ---------------------------------------------------------------------------
// Direct-from-global NT GEMM (round-2 kernel) — kept for the small per-head
// attention GEMMs (K=64 / 672) where LDS staging can't amortize.
// ---------------------------------------------------------------------------
template <int EPI, int M, int N, int K, int LDA, int LDB>
__global__ __launch_bounds__(256) void gemm_nt(
    const __bf16* __restrict__ A, const __bf16* __restrict__ B,
    const float* __restrict__ bias, const __bf16* __restrict__ aux,
    const int* __restrict__ mask, __bf16* __restrict__ out)
{
  constexpr int MT  = M / 16;
  constexpr int NT4 = (N + 63) / 64;
  const int lane = threadIdx.x & 63;
  const int wid  = threadIdx.x >> 6;
  const int tile = blockIdx.x * 4 + wid;
  if (tile >= MT * NT4) return;
  const int im = tile / NT4, in = tile % NT4;
  const int z = blockIdx.y;
  int b = 0, h = 0;
  size_t aoff = 0, boff = 0;
  if constexpr (EPI == E_R) {
    b = z / Hh; h = z % Hh;
    aoff = (size_t)b * Ss * Dd + h * DH;
  } else if constexpr (EPI == E_SC) {
    b = z / Hh; h = z % Hh;
    aoff = (size_t)b * Ss * Dd + h * DH;
    boff = aoff;
  } else if constexpr (EPI == E_CTX) {
    b = z / Hh; h = z % Hh;
    aoff = (size_t)z * Ss * PLD;
    boff = (size_t)z * DH * PLD;
  }

  const __bf16* Ap = A + aoff + (size_t)(im * 16 + (lane & 15)) * LDA + ((lane >> 4) * 8);
  const __bf16* Bp = B + boff + (size_t)(lane & 15) * LDB + ((lane >> 4) * 8);

  floatx4 acc[4] = {};
  for (int k = 0; k < K; k += 32) {
    bf16x8 av = *(const bf16x8*)(Ap + k);
#pragma unroll
    for (int t = 0; t < 4; ++t) {
      bf16x8 bv = *(const bf16x8*)(Bp + (size_t)(in * 64 + t * 16) * LDB + k);
      acc[t] = __builtin_amdgcn_mfma_f32_16x16x32_bf16(av, bv, acc[t], 0, 0, 0);
    }
  }

  const int mb = im * 16 + ((lane >> 4) << 2);
#pragma unroll
  for (int t = 0; t < 4; ++t) {
    const int n = in * 64 + t * 16 + (lane & 15);
    if constexpr (N % 64 != 0) { if (n >= N) continue; }
    if constexpr (EPI == E_R) {
#pragma unroll
      for (int r = 0; r < 4; ++r)
        out[((size_t)z * Ss + mb + r) * RLD + n] = (__bf16)(acc[t][r]);
    } else if constexpr (EPI == E_SC) {
      const float mbias = (1.0f - (float)mask[b * Ss + n]) * -10000.0f;
#pragma unroll
      for (int r = 0; r < 4; ++r) {
        const int q = mb + r;
        int rr = n - q; rr = rr < -64 ? -64 : (rr > 64 ? 64 : rr); rr += 64;
        const float rv = (float)aux[((size_t)z * Ss + q) * RLD + rr];
        out[((size_t)z * Ss + q) * PLD + n] = (__bf16)((acc[t][r] + rv) * 0.125f + mbias);
      }
    } else if constexpr (EPI == E_CTX) {
#pragma unroll
      for (int r = 0; r < 4; ++r) {
        const int q = mb + r;
        out[(size_t)(b * Ss + q) * Dd + h * DH + n] = (__bf16)(acc[t][r]);
      }
    }
  }
}

// softmax over scores row (512, bf16 in-place -> probs) + Prow bucket sums
// into [512:672]: r=0 tail (k<=q-64), r=128 tail (k>=q+64), r=1..127 gather.
__global__ __launch_bounds__(256) void softmax_rel(__bf16* __restrict__ pbuf)
{
  __shared__ float sm[4][512];
  const int lane = threadIdx.x & 63, wid = threadIdx.x >> 6;
  const size_t row = (size_t)blockIdx.x * 4 + wid;
  const int q = (int)(row & (Ss - 1));
  __bf16* p = pbuf + row * PLD;
  bf16x8 sv = *(const bf16x8*)(p + lane * 8);
  float x[8], mx = -3.0e38f;
#pragma unroll
  for (int j = 0; j < 8; ++j) { x[j] = (float)sv[j]; mx = fmaxf(mx, x[j]); }
  mx = wredmax(mx);
  float s = 0.f;
#pragma unroll
  for (int j = 0; j < 8; ++j) { x[j] = __expf(x[j] - mx); s += x[j]; }
  s = wredsum(s);
  const float inv = 1.0f / s;
  float t0 = 0.f, t1 = 0.f;
  const int base = lane * 8;
  bf16x8 ov;
#pragma unroll
  for (int j = 0; j < 8; ++j) {
    const float pv = x[j] * inv;
    ov[j] = (__bf16)pv;
    sm[wid][base + j] = pv;
    const int kk = base + j;
    if (kk <= q - 64) t0 += pv;
    if (kk >= q + 64) t1 += pv;
  }
  *(bf16x8*)(p + lane * 8) = ov;
  t0 = wredsum(t0);
  t1 = wredsum(t1);
  __syncthreads();
  for (int r = lane; r < RLD; r += 64) {
    float v;
    if (r == 0) v = t0;
    else if (r == 128) v = t1;
    else if (r < 128) { const int kk = q + r - 64; v = (kk >= 0 && kk < Ss) ? sm[wid][kk] : 0.f; }
    else v = 0.f;
    p[Ss + r] = (__bf16)v;
  }
}

template <typename OutT>
__global__ __launch_bounds__(256) void ln_rows(
    const __bf16* __restrict__ x, const float* __restrict__ wv,
    const float* __restrict__ bv, OutT* __restrict__ out)
{
  __shared__ float red[4];
  const int row = blockIdx.x, t = threadIdx.x;
  const __bf16* xr = x + (size_t)row * Dd;
  float xv[3], s = 0.f;
#pragma unroll
  for (int j = 0; j < 3; ++j) { xv[j] = (float)xr[t + 256 * j]; s += xv[j]; }
  s = wredsum(s);
  if ((t & 63) == 0) red[t >> 6] = s;
  __syncthreads();
  const float mean = (red[0] + red[1] + red[2] + red[3]) * (1.0f / Dd);
  __syncthreads();
  float qq = 0.f;
#pragma unroll
  for (int j = 0; j < 3; ++j) { const float d = xv[j] - mean; qq += d * d; }
  qq = wredsum(qq);
  if ((t & 63) == 0) red[t >> 6] = qq;
  __syncthreads();
  const float var = (red[0] + red[1] + red[2] + red[3]) * (1.0f / Dd);
  const float rs = rsqrtf(var + LN_EPS);
#pragma unroll
  for (int j = 0; j < 3; ++j) {
    const int i = t + 256 * j;
    out[(size_t)row * Dd + i] = (OutT)((xv[j] - mean) * rs * wv[i] + bv[i]);
  }
}

__global__ __launch_bounds__(256) void embed_ln(
    const int* __restrict__ ids, const int* __restrict__ tts,
    const float* __restrict__ we, const float* __restrict__ te,
    const float* __restrict__ wv, const float* __restrict__ bv,
    __bf16* __restrict__ out)
{
  __shared__ float red[4];
  const int row = blockIdx.x, t = threadIdx.x;
  const int id = ids[row], tt = tts[row];
  const float* wr = we + (size_t)id * Dd;
  const float* tr = te + (size_t)tt * Dd;
  float xv[3], s = 0.f;
#pragma unroll
  for (int j = 0; j < 3; ++j) {
    const int i = t + 256 * j;
    xv[j] = wr[i] + tr[i];
    s += xv[j];
  }
  s = wredsum(s);
  if ((t & 63) == 0) red[t >> 6] = s;
  __syncthreads();
  const float mean = (red[0] + red[1] + red[2] + red[3]) * (1.0f / Dd);
  __syncthreads();
  float qq = 0.f;
#pragma unroll
  for (int j = 0; j < 3; ++j) { const float d = xv[j] - mean; qq += d * d; }
  qq = wredsum(qq);
  if ((t & 63) == 0) red[t >> 6] = qq;
  __syncthreads();
  const float var = (red[0] + red[1] + red[2] + red[3]) * (1.0f / Dd);
  const float rs = rsqrtf(var + LN_EPS);
#pragma unroll
  for (int j = 0; j < 3; ++j) {
    const int i = t + 256 * j;
    out[(size_t)row * Dd + i] = (__bf16)((xv[j] - mean) * rs * wv[i] + bv[i]);
  }
}

// fp32 -> bf16 bulk convert (n % 4 == 0)
__global__ __launch_bounds__(256) void f2b(
    const float* __restrict__ in, __bf16* __restrict__ out, int n4)
{
  const int i = blockIdx.x * 256 + threadIdx.x;
  if (i >= n4) return;
  const float4 v = ((const float4*)in)[i];
  bf16x4 o;
  o[0] = (__bf16)v.x; o[1] = (__bf16)v.y; o[2] = (__bf16)v.z; o[3] = (__bf16)v.w;
  *(bf16x4*)(out + (size_t)i * 4) = o;
}

// Fill the T^T block of vte: vte[bh][d][512+r] = rel[64][r][d] (r<129), else 0.
__global__ __launch_bounds__(256) void prep_rel(
    const float* __restrict__ rel, __bf16* __restrict__ vte)
{
  const int idx = blockIdx.x * 256 + threadIdx.x;
  constexpr int TOT = BH * DH * RLD;
  if (idx >= TOT) return;
  const int r = idx % RLD, t2 = idx / RLD;
  const int d = t2 % DH, bh = t2 / DH;
  __bf16 v = (__bf16)0.f;
  if (r < 129) v = (__bf16)rel[((size_t)(64 * Ss + r)) * DH + d];
  vte[((size_t)bh * DH + d) * PLD + Ss + r] = v;
}

// Tb[r][d] = rel[64][r][d] for r<129 else 0; 192 rows (E_R reads up to 191).
__global__ __launch_bounds__(256) void rel2b(
    const float* __restrict__ rel, __bf16* __restrict__ Tb)
{
  const int idx = blockIdx.x * 256 + threadIdx.x;  // < 192*64
  const int d = idx & 63, r = idx >> 6;
  float v = (r < 129) ? rel[((size_t)(64 * Ss + r)) * DH + d] : 0.f;
  Tb[idx] = (__bf16)v;
}

extern "C" void kernel_launch(void* const* d_in, const int* in_sizes, int n_in,
                              void* d_out, int out_size, void* d_ws, size_t ws_size,
                              hipStream_t stream)
{
  (void)in_sizes; (void)n_in; (void)out_size; (void)ws_size;
  const int*   ids  = (const int*)d_in[0];
  const int*   mask = (const int*)d_in[1];
  const int*   tts  = (const int*)d_in[2];
  const float* wemb = (const float*)d_in[3];
  const float* temb = (const float*)d_in[4];
  const float* elw  = (const float*)d_in[5];
  const float* elb  = (const float*)d_in[6];
  const float* qw   = (const float*)d_in[7];
  const float* qb   = (const float*)d_in[8];
  const float* kw   = (const float*)d_in[9];
  const float* kb   = (const float*)d_in[10];
  const float* vw   = (const float*)d_in[11];
  const float* vb   = (const float*)d_in[12];
  const float* rel  = (const float*)d_in[13];
  const float* aow  = (const float*)d_in[14];
  const float* aob  = (const float*)d_in[15];
  const float* alw  = (const float*)d_in[16];
  const float* alb  = (const float*)d_in[17];
  const float* iw   = (const float*)d_in[18];
  const float* ib   = (const float*)d_in[19];
  const float* ow   = (const float*)d_in[20];
  const float* ob   = (const float*)d_in[21];
  const float* olw  = (const float*)d_in[22];
  const float* olb  = (const float*)d_in[23];

  char* wsb = (char*)d_ws;
  size_t off = 0;
  auto alloc = [&](size_t elems) {
    __bf16* p = (__bf16*)(wsb + off);
    off += elems * sizeof(__bf16);
    return p;
  };
  constexpr size_t HB  = (size_t)Bb * Ss * Dd;         // 6.29M elems
  constexpr size_t WQ  = (size_t)Dd * Dd;              // one 768x768
  constexpr size_t WI  = (size_t)Ll * FF * Dd;         // 9.44M
  __bf16* qkvw_b = alloc((size_t)Ll * 3 * WQ);         // [l][2304][768]
  __bf16* aw_b = alloc((size_t)Ll * WQ);
  __bf16* iw_b = alloc(WI);
  __bf16* ow_b = alloc(WI);
  __bf16* hbuf = alloc(HB);                            // hidden state
  __bf16* abuf = alloc(HB);                            // attn-LN output
  __bf16* qbuf = alloc(HB);                            // also aliased as s1
  __bf16* kbuf = alloc(HB);
  __bf16* ctx  = alloc(HB);
  __bf16* vte  = alloc((size_t)BH * DH * PLD);         // [V^T | T^T] per (b,h)
  __bf16* pb   = alloc((size_t)BH * Ss * PLD);         // [scores/probs | Prow]
  __bf16* fbuf = alloc((size_t)Bb * Ss * FF);          // GELU out; Rb aliases
  __bf16* Tb   = alloc((size_t)192 * DH);              // bf16 rel table
  __bf16* s1   = qbuf;                                 // alias: free after E_SC
  __bf16* Rb   = fbuf;                                 // alias: free until GELU

  // weight converts: QKV interleaved per layer as [Q(768)|K(768)|V(768)] x 768
  for (int l = 0; l < Ll; ++l) {
    f2b<<<(int)((WQ / 4 + 255) / 256), 256, 0, stream>>>(
        qw + (size_t)l * WQ, qkvw_b + ((size_t)l * 3 + 0) * WQ, (int)(WQ / 4));
    f2b<<<(int)((WQ / 4 + 255) / 256), 256, 0, stream>>>(
        kw + (size_t)l * WQ, qkvw_b + ((size_t)l * 3 + 1) * WQ, (int)(WQ / 4));
    f2b<<<(int)((WQ / 4 + 255) / 256), 256, 0, stream>>>(
        vw + (size_t)l * WQ, qkvw_b + ((size_t)l * 3 + 2) * WQ, (int)(WQ / 4));
  }
  f2b<<<(int)((Ll * WQ / 4 + 255) / 256), 256, 0, stream>>>(aow, aw_b, (int)(Ll * WQ / 4));
  f2b<<<(int)((WI / 4 + 255) / 256), 256, 0, stream>>>(iw, iw_b, (int)(WI / 4));
  f2b<<<(int)((WI / 4 + 255) / 256), 256, 0, stream>>>(ow, ow_b, (int)(WI / 4));
  rel2b<<<(192 * DH) / 256, 256, 0, stream>>>(rel, Tb);
  prep_rel<<<(BH * DH * RLD + 255) / 256, 256, 0, stream>>>(rel, vte);
  embed_ln<<<Bb * Ss, 256, 0, stream>>>(ids, tts, wemb, temb, elw, elb, hbuf);

  for (int l = 0; l < Ll; ++l) {
    const __bf16* qkvwl = qkvw_b + (size_t)l * 3 * WQ;
    const float*  qbl = qb + (size_t)l * Dd;
    const float*  kbl = kb + (size_t)l * Dd;
    const float*  vbl = vb + (size_t)l * Dd;
    const __bf16* awl = aw_b + (size_t)l * WQ;       const float* abl = aob + (size_t)l * Dd;
    const float*  lw1 = alw + (size_t)l * Dd;        const float* lb1 = alb + (size_t)l * Dd;
    const __bf16* iwl = iw_b + (size_t)l * FF * Dd;  const float* ibl = ib + (size_t)l * FF;
    const __bf16* owl = ow_b + (size_t)l * FF * Dd;  const float* obl = ob + (size_t)l * Dd;
    const float*  lw2 = olw + (size_t)l * Dd;        const float* lb2 = olb + (size_t)l * Dd;

    // fused QKV: (8192 x 2304) = hbuf @ [q|k|v]^T, writes qbuf, kbuf, vte
    gemm128<E_QKV, 2304, 768><<<64 * 18, 256, 0, stream>>>(
        hbuf, qkvwl, qbl, kbl, vbl, nullptr, qbuf, kbuf, vte);
    gemm_nt<E_R, 512, 129, 64, 768, 64><<<dim3(24, BH), 256, 0, stream>>>(
        qbuf, Tb, nullptr, nullptr, nullptr, Rb);
    gemm_nt<E_SC, 512, 512, 64, 768, 768><<<dim3(64, BH), 256, 0, stream>>>(
        qbuf, kbuf, nullptr, Rb, mask, pb);
    softmax_rel<<<BH * Ss / 4, 256, 0, stream>>>(pb);
    gemm_nt<E_CTX, 512, 64, 672, 672, 672><<<dim3(8, BH), 256, 0, stream>>>(
        pb, vte, nullptr, nullptr, nullptr, ctx);
    gemm128<E_RES, 768, 768><<<64 * 6, 256, 0, stream>>>(
        ctx, awl, abl, nullptr, nullptr, hbuf, s1, nullptr, nullptr);
    ln_rows<__bf16><<<8192, 256, 0, stream>>>(s1, lw1, lb1, abuf);
    gemm128<E_GELU, 3072, 768><<<64 * 24, 256, 0, stream>>>(
        abuf, iwl, ibl, nullptr, nullptr, nullptr, fbuf, nullptr, nullptr);
    gemm128<E_RES, 768, 3072><<<64 * 6, 256, 0, stream>>>(
        fbuf, owl, obl, nullptr, nullptr, abuf, s1, nullptr, nullptr);
    if (l == Ll - 1)
      ln_rows<float><<<8192, 256, 0, stream>>>(s1, lw2, lb2, (float*)d_out);
    else
      ln_rows<__bf16><<<8192, 256, 0, stream>>>(s1, lw2, lb2, hbuf);
  }
}